// Round 12
// baseline (90.497 us; speedup 1.0000x reference)
//
#include <hip/hip_runtime.h>
#include <hip/hip_bf16.h>

typedef __bf16 bf16x8 __attribute__((ext_vector_type(8)));
typedef unsigned short u16x8 __attribute__((ext_vector_type(8)));
typedef unsigned int u32x4 __attribute__((ext_vector_type(4)));
typedef float f32x4 __attribute__((ext_vector_type(4)));

#define SLEN 2048
#define DDIM 128
#define NH   32
#define NKVH 8
#define KVB  32
#define MINIT  -1e30f
#define MASKED -3e30f
#define LOG2E  1.4426950408889634f

static __device__ __forceinline__ unsigned short f2bfu(float f) {
  union { float f; unsigned u; } x; x.f = f;
  return (unsigned short)((x.u + 0x7fffu + ((x.u >> 16) & 1u)) >> 16);
}
static __device__ __forceinline__ float bfu2f(unsigned short u) {
  union { unsigned u; float f; } x; x.u = ((unsigned)u) << 16;
  return x.f;
}
static __device__ __forceinline__ unsigned cvt_pk_bf16(float lo, float hi) {
  unsigned r;
  asm("v_cvt_pk_bf16_f32 %0, %1, %2" : "=v"(r) : "v"(lo), "v"(hi));
  return r;
}
static __device__ __forceinline__ f32x4 mfma_bf16(u16x8 a, u16x8 b, f32x4 c) {
  return __builtin_amdgcn_mfma_f32_16x16x32_bf16(
      __builtin_bit_cast(bf16x8, a), __builtin_bit_cast(bf16x8, b), c, 0, 0, 0);
}
static __device__ __forceinline__ int vswz_k(int row) {
  return (row & 3) | (((row >> 3) & 1) << 2);
}

// ---- fused prepass: K -> bf16 (blocks 0..1023), V -> bf16 transposed (1024..3071) ----
__global__ __launch_bounds__(256) void conv_kv(const float* __restrict__ k,
                                               const float* __restrict__ v,
                                               unsigned* __restrict__ kdst,
                                               unsigned short* __restrict__ vt) {
  __shared__ unsigned T32[32][17];
  const int bb = blockIdx.x;
  if (bb < 1024) {
    const int i = bb * 256 + threadIdx.x;
    const float4 f0 = ((const float4*)k)[2 * i];
    const float4 f1 = ((const float4*)k)[2 * i + 1];
    u32x4 o = { cvt_pk_bf16(f0.x, f0.y), cvt_pk_bf16(f0.z, f0.w),
                cvt_pk_bf16(f1.x, f1.y), cvt_pk_bf16(f1.z, f1.w) };
    ((u32x4*)kdst)[i] = o;
    return;
  }
  const int b   = bb - 1024;
  const int dt  = b & 3;
  const int st  = (b >> 2) & 63;
  const int kvh = b >> 8;
  const int r  = threadIdx.x >> 3;
  const int cg = threadIdx.x & 7;
  const float4 f = *(const float4*)(v + ((size_t)(kvh * SLEN + st * 32 + r) * DDIM) + dt * 32 + cg * 4);
  T32[r][cg * 2]     = cvt_pk_bf16(f.x, f.y);
  T32[r][cg * 2 + 1] = cvt_pk_bf16(f.z, f.w);
  __syncthreads();
  const int dr = threadIdx.x >> 3;
  const unsigned sel = (dr & 1) ? 0x07060302u : 0x05040100u;
  const unsigned a0 = T32[cg * 4 + 0][dr >> 1], a1 = T32[cg * 4 + 1][dr >> 1];
  const unsigned a2 = T32[cg * 4 + 2][dr >> 1], a3 = T32[cg * 4 + 3][dr >> 1];
  unsigned short* vp = vt + (size_t)kvh * DDIM * SLEN + (size_t)(dt * 32 + dr) * SLEN + st * 32 + cg * 4;
  const unsigned w0 = __builtin_amdgcn_perm(a1, a0, sel);
  const unsigned w1 = __builtin_amdgcn_perm(a3, a2, sel);
  vp[0] = (unsigned short)(w0 & 0xffff);
  vp[1] = (unsigned short)(w0 >> 16);
  vp[2] = (unsigned short)(w1 & 0xffff);
  vp[3] = (unsigned short)(w1 >> 16);
}

// ---- attention: 32 q-rows/wave (2 groups), swapped QK^T + K-row perm, in-reg P ----
template <int NCH>
__global__ __launch_bounds__(256, 3) void attn_fwd(
    const float* __restrict__ q, const unsigned short* __restrict__ kbf,
    const unsigned short* __restrict__ vtg, const float* __restrict__ sinks,
    const int* __restrict__ bwp, float* __restrict__ out,
    unsigned short* __restrict__ pO, float* __restrict__ pm,
    float* __restrict__ pl) {
  constexpr int QBLK = 128;               // 4 waves x 32 q-rows
  constexpr int NQT  = SLEN / QBLK;       // 16
  __shared__ unsigned short Kl[KVB * DDIM];   // unpadded, slot-swizzled
  __shared__ unsigned short Vt[DDIM * KVB];   // unpadded, slot-swizzled
  __shared__ float SmS[4][2][16];

  const int tid  = threadIdx.x;
  const int wid  = tid >> 6;
  const int lane = tid & 63;
  const int ln   = lane & 15;
  const int hi   = lane >> 4;

  const int B   = blockIdx.x;
  const int x   = B & 7;                  // XCD-resident kvh
  const int j   = B >> 3;
  constexpr int per = 4 * NCH;
  const int qt  = NQT - 1 - (j / per);    // descending: long chunks first
  const int rem = j % per;
  const int hh  = rem / NCH;
  const int c   = rem % NCH;
  const int h   = x * 4 + hh;
  const int kvh = x;
  const int q0  = qt * QBLK;
  const int qrow0 = q0 + wid * 32;        // wave's 32 rows

  const int bwv    = bwp[0];
  const int lo_off = (bwv > 0) ? (bwv - 1) : SLEN;

  const int T0 = max(0, q0 - lo_off) >> 5;
  const int T1 = (q0 + QBLK - 1) >> 5;
  const int N  = T1 - T0 + 1;
  const int ch = (N + NCH - 1) / NCH;
  const int Ts = T0 + c * ch;
  const int Te = min(T1, Ts + ch - 1);

  const float c2 = 0.08838834764831845f * LOG2E;  // sm_scale * log2e

  // ---- Q fragments (MFMA B-operand after swap): group g rows = qrow0+g*16+ln ----
  u16x8 qf[2][4];
  #pragma unroll
  for (int g = 0; g < 2; ++g) {
    const float* qp = q + ((size_t)(h * SLEN + qrow0 + g * 16 + ln) * DDIM) + hi * 8;
    #pragma unroll
    for (int dk = 0; dk < 4; ++dk) {
      float4 f0 = *(const float4*)(qp + dk * 32);
      float4 f1 = *(const float4*)(qp + dk * 32 + 4);
      u32x4 t = { cvt_pk_bf16(f0.x, f0.y), cvt_pk_bf16(f0.z, f0.w),
                  cvt_pk_bf16(f1.x, f1.y), cvt_pk_bf16(f1.z, f1.w) };
      qf[g][dk] = __builtin_bit_cast(u16x8, t);
    }
  }

  float m2[2] = {MINIT, MINIT}, l[2] = {0.0f, 0.0f};  // log2-domain running max
  f32x4 oacc[2][8];
  #pragma unroll
  for (int g = 0; g < 2; ++g)
    #pragma unroll
    for (int nt = 0; nt < 8; ++nt) oacc[g][nt] = f32x4{0.f, 0.f, 0.f, 0.f};

  const unsigned short* Kg = kbf + (size_t)kvh * SLEN * DDIM;
  const unsigned short* Vg = vtg + (size_t)kvh * DDIM * SLEN;

  // ---- staging coords (R11): global linear, LDS slot-swizzled ----
  const int kr0 = tid >> 4, sk = tid & 15;
  const int kr1 = kr0 + 16;
  const int kw0 = kr0 * DDIM + (((sk & 8) | ((sk & 7) ^ vswz_k(kr0))) * 8);
  const int kw1 = kr1 * DDIM + (((sk & 8) | ((sk & 7) ^ vswz_k(kr1))) * 8);
  const int vr0 = tid >> 2, sv = tid & 3;
  const int vr1 = vr0 + 64;
  const int vw0 = vr0 * KVB + ((sv ^ ((vr0 >> 1) & 3)) * 8);
  const int vw1 = vr1 * KVB + ((sv ^ ((vr1 >> 1) & 3)) * 8);

  // ---- read offsets (R11): K rows permuted so lane holds k = hi*8+0..7 ----
  const int prow = ((ln >> 2) << 3) | (ln & 3);
  const int vk   = (ln & 3) | (((ln >> 2) & 1) << 2);
  int kfo[4];
  #pragma unroll
  for (int dk = 0; dk < 4; ++dk) {
    const int s = dk * 4 + hi;
    kfo[dk] = prow * DDIM + (((s & 8) | ((s & 7) ^ vk)) * 8);
  }
  const int vro = ln * KVB + ((hi ^ ((ln >> 1) & 3)) * 8);

  if (Ts <= Te) {
    const int kbS = Ts * 32, kbE = Te * 32;

    u16x8 pk0, pk1, pv0, pv1;
    {
      pk0 = *(const u16x8*)(Kg + (size_t)(kbS + kr0) * DDIM + sk * 8);
      pk1 = *(const u16x8*)(Kg + (size_t)(kbS + kr1) * DDIM + sk * 8);
      pv0 = *(const u16x8*)(Vg + (size_t)vr0 * SLEN + kbS + sv * 8);
      pv1 = *(const u16x8*)(Vg + (size_t)vr1 * SLEN + kbS + sv * 8);
    }

    for (int kb = kbS; kb <= kbE; kb += KVB) {
      __syncthreads();
      *(u16x8*)&Kl[kw0] = pk0;
      *(u16x8*)&Kl[kw1] = pk1;
      *(u16x8*)&Vt[vw0] = pv0;
      *(u16x8*)&Vt[vw1] = pv1;
      __syncthreads();

      {
        const int nb = min(kb + KVB, kbE);
        pk0 = *(const u16x8*)(Kg + (size_t)(nb + kr0) * DDIM + sk * 8);
        pk1 = *(const u16x8*)(Kg + (size_t)(nb + kr1) * DDIM + sk * 8);
        pv0 = *(const u16x8*)(Vg + (size_t)vr0 * SLEN + nb + sv * 8);
        pv1 = *(const u16x8*)(Vg + (size_t)vr1 * SLEN + nb + sv * 8);
      }

      if (kb > qrow0 + 31) continue;                 // above causal diag (wave)
      if (kb + KVB - 1 < qrow0 - lo_off) continue;   // before window (wave)

      // ---- QK^T (swapped, K rows permuted): each K read feeds both groups ----
      f32x4 sacc[2][2];
      #pragma unroll
      for (int g = 0; g < 2; ++g) { sacc[g][0] = f32x4{0,0,0,0}; sacc[g][1] = f32x4{0,0,0,0}; }
      #pragma unroll
      for (int dk = 0; dk < 4; ++dk) {
        const u16x8 kf0 = *(const u16x8*)&Kl[kfo[dk]];              // rows perm
        const u16x8 kf1 = *(const u16x8*)&Kl[kfo[dk] + 4 * DDIM];   // rows perm+4
        sacc[0][0] = mfma_bf16(kf0, qf[0][dk], sacc[0][0]);
        sacc[1][0] = mfma_bf16(kf0, qf[1][dk], sacc[1][0]);
        sacc[0][1] = mfma_bf16(kf1, qf[0][dk], sacc[0][1]);
        sacc[1][1] = mfma_bf16(kf1, qf[1][dk], sacc[1][1]);
      }

      // ---- scale to log2 domain + mask (interior fast path, wave-uniform) ----
      float p[2][8];
      const bool interior = (kb + KVB - 1 <= qrow0) && (kb >= qrow0 + 31 - lo_off);
      if (interior) {
        #pragma unroll
        for (int g = 0; g < 2; ++g)
          #pragma unroll
          for (int r = 0; r < 4; ++r) {
            p[g][r]     = sacc[g][0][r] * c2;
            p[g][4 + r] = sacc[g][1][r] * c2;
          }
      } else {
        #pragma unroll
        for (int g = 0; g < 2; ++g) {
          const int qpos = qrow0 + g * 16 + ln;
          #pragma unroll
          for (int r = 0; r < 4; ++r) {
            const int kp0 = kb + hi * 8 + r;
            const int kp1 = kp0 + 4;
            p[g][r]     = ((kp0 <= qpos) && (kp0 >= qpos - lo_off)) ? sacc[g][0][r] * c2 : MASKED;
            p[g][4 + r] = ((kp1 <= qpos) && (kp1 >= qpos - lo_off)) ? sacc[g][1][r] * c2 : MASKED;
          }
        }
      }

      // ---- row max per group: 7 in-reg + 2 shfl ----
      float mx[2];
      bool need = false;
      #pragma unroll
      for (int g = 0; g < 2; ++g) {
        float t = fmaxf(fmaxf(fmaxf(p[g][0], p[g][1]), fmaxf(p[g][2], p[g][3])),
                        fmaxf(fmaxf(p[g][4], p[g][5]), fmaxf(p[g][6], p[g][7])));
        t = fmaxf(t, __shfl_xor(t, 16));
        t = fmaxf(t, __shfl_xor(t, 32));
        mx[g] = t;
        need = need || (t > m2[g] + 11.5415605f);   // THR = 8 nats in log2 units
      }

      // ---- defer-max rescale ----
      if (__any(need)) {
        #pragma unroll
        for (int g = 0; g < 2; ++g) {
          const float mn   = fmaxf(m2[g], mx[g]);
          const float corr = exp2f(m2[g] - mn);
          l[g] *= corr;
          m2[g] = mn;
          if (hi == 0) SmS[wid][g][ln] = corr;
        }
        #pragma unroll
        for (int g = 0; g < 2; ++g) {
          float c4[4];
          #pragma unroll
          for (int r = 0; r < 4; ++r) c4[r] = SmS[wid][g][hi * 4 + r];
          #pragma unroll
          for (int nt = 0; nt < 8; ++nt)
            #pragma unroll
            for (int r = 0; r < 4; ++r) oacc[g][nt][r] *= c4[r];
        }
      }

      // ---- exp2 + row sum per group ----
      #pragma unroll
      for (int g = 0; g < 2; ++g) {
        float s = 0.0f;
        #pragma unroll
        for (int jj = 0; jj < 8; ++jj) { p[g][jj] = exp2f(p[g][jj] - m2[g]); s += p[g][jj]; }
        s += __shfl_xor(s, 16);
        s += __shfl_xor(s, 32);
        l[g] += s;
      }

      // ---- P -> bf16 A-frags, entirely in registers ----
      u16x8 pa[2];
      #pragma unroll
      for (int g = 0; g < 2; ++g) {
        const u32x4 paw = { cvt_pk_bf16(p[g][0], p[g][1]), cvt_pk_bf16(p[g][2], p[g][3]),
                            cvt_pk_bf16(p[g][4], p[g][5]), cvt_pk_bf16(p[g][6], p[g][7]) };
        pa[g] = __builtin_bit_cast(u16x8, paw);
      }

      // ---- PV: each V read feeds both groups ----
      #pragma unroll
      for (int nt = 0; nt < 8; ++nt) {
        const u16x8 vb = *(const u16x8*)&Vt[vro + nt * 16 * KVB];
        oacc[0][nt] = mfma_bf16(pa[0], vb, oacc[0][nt]);
        oacc[1][nt] = mfma_bf16(pa[1], vb, oacc[1][nt]);
      }
    }
  }

  // ---- epilogue ----
  if (NCH == 1) {
    const float sk2 = sinks[h] * LOG2E;
    #pragma unroll
    for (int g = 0; g < 2; ++g) {
      const float M  = fmaxf(m2[g], sk2);
      const float ed = exp2f(m2[g] - M);
      const float fac_ln = ed / (l[g] * ed + exp2f(sk2 - M));
      if (hi == 0) SmS[wid][g][ln] = fac_ln;
      float fac4[4];
      #pragma unroll
      for (int r = 0; r < 4; ++r) fac4[r] = SmS[wid][g][hi * 4 + r];
      #pragma unroll
      for (int r = 0; r < 4; ++r) {
        float* op = out + ((size_t)(h * SLEN + qrow0 + g*16 + hi*4 + r) * DDIM) + ln;
        #pragma unroll
        for (int nt = 0; nt < 8; ++nt) op[nt * 16] = oacc[g][nt][r] * fac4[r];
      }
    }
  } else {
    const size_t Lb = ((size_t)(h * NQT + qt)) * NCH + c;
    #pragma unroll
    for (int g = 0; g < 2; ++g) {
      const int rbase = wid * 32 + g * 16;
      if (hi == 0) {
        pm[Lb * QBLK + rbase + ln] = m2[g];   // log2 domain
        pl[Lb * QBLK + rbase + ln] = l[g];
      }
      #pragma unroll
      for (int r = 0; r < 4; ++r) {
        unsigned short* po = pO + (Lb * QBLK + rbase + hi * 4 + r) * 128 + ln;
        #pragma unroll
        for (int nt = 0; nt < 8; ++nt) po[nt * 16] = f2bfu(oacc[g][nt][r]);
      }
    }
  }
}

// ---- merge NCH chunk partials + sink (log2-domain stats) ----
template <int NCH, int QBLK, int NQT>
__global__ __launch_bounds__(256) void mergeN(
    const unsigned short* __restrict__ pO, const float* __restrict__ pm,
    const float* __restrict__ pl, const float* __restrict__ sinks,
    float* __restrict__ out) {
  const int t    = blockIdx.x * 256 + threadIdx.x;
  const int rid  = t >> 2;
  const int d0   = (t & 3) * 32;
  const int h    = rid >> 11;
  const int qpos = rid & 2047;
  const int qt   = qpos / QBLK;
  const int lr   = qpos % QBLK;
  const size_t base = ((size_t)(h * NQT + qt) * NCH) * QBLK + lr;
  const float sk2 = sinks[h] * LOG2E;
  float mc[NCH], lc[NCH];
  float M = sk2;
  #pragma unroll
  for (int c = 0; c < NCH; ++c) {
    mc[c] = pm[base + (size_t)c * QBLK];
    lc[c] = pl[base + (size_t)c * QBLK];
    M = fmaxf(M, mc[c]);
  }
  float denom = exp2f(sk2 - M);
  float sc[NCH];
  #pragma unroll
  for (int c = 0; c < NCH; ++c) { sc[c] = exp2f(mc[c] - M); denom += lc[c] * sc[c]; }
  const float inv = 1.0f / denom;
  float o[32];
  #pragma unroll
  for (int i = 0; i < 32; ++i) o[i] = 0.f;
  #pragma unroll
  for (int c = 0; c < NCH; ++c) {
    const unsigned short* pp = pO + (base + (size_t)c * QBLK) * 128 + d0;
    const float s = sc[c] * inv;
    #pragma unroll
    for (int i = 0; i < 4; ++i) {
      u16x8 a = *(const u16x8*)(pp + i * 8);
      #pragma unroll
      for (int jj = 0; jj < 8; ++jj) o[i*8+jj] += bfu2f(a[jj]) * s;
    }
  }
  float* op = out + (size_t)rid * 128 + d0;
  #pragma unroll
  for (int i = 0; i < 8; ++i)
    *(float4*)(op + i*4) = make_float4(o[i*4], o[i*4+1], o[i*4+2], o[i*4+3]);
}

extern "C" void kernel_launch(void* const* d_in, const int* in_sizes, int n_in,
                              void* d_out, int out_size, void* d_ws, size_t ws_size,
                              hipStream_t stream) {
  const float* q     = (const float*)d_in[0];
  const float* k     = (const float*)d_in[1];
  const float* v     = (const float*)d_in[2];
  const float* sinks = (const float*)d_in[3];
  const int*   bw    = (const int*)d_in[4];
  float* out = (float*)d_out;

  const size_t kvElems = (size_t)NKVH * SLEN * DDIM;
  unsigned short* kbf = (unsigned short*)d_ws;
  unsigned short* vtg = kbf + kvElems;
  unsigned short* pO  = vtg + kvElems;

  // NCH=2, QBLK=128: partial rows = 32h * 16qt * 2c * 128 rows
  const size_t nPart2 = (size_t)NH * 16 * 2 * 128;
  const size_t need2  = 4 * kvElems + nPart2 * 128 * 2 + nPart2 * 8;  // ~51.4 MB

  conv_kv<<<dim3(1024 + NKVH * 64 * 4), 256, 0, stream>>>(k, v, (unsigned*)kbf, vtg);

  if (ws_size >= need2) {
    float* pm = (float*)(pO + nPart2 * 128);
    float* pl = pm + nPart2;
    attn_fwd<2><<<dim3(1024), 256, 0, stream>>>(q, kbf, vtg, sinks, bw, out, pO, pm, pl);
    mergeN<2, 128, 16><<<dim3(1024), 256, 0, stream>>>(pO, pm, pl, sinks, out);
  } else {
    attn_fwd<1><<<dim3(512), 256, 0, stream>>>(q, kbf, vtg, sinks, bw, out, pO, nullptr, nullptr);
  }
}

// Round 13
// 77.752 us; speedup vs baseline: 1.1639x; 1.1639x over previous
//
#include <hip/hip_runtime.h>
#include <hip/hip_bf16.h>

typedef __bf16 bf16x8 __attribute__((ext_vector_type(8)));
typedef unsigned short u16x8 __attribute__((ext_vector_type(8)));
typedef unsigned int u32x4 __attribute__((ext_vector_type(4)));
typedef float f32x4 __attribute__((ext_vector_type(4)));

#define SLEN 2048
#define DDIM 128
#define NH   32
#define NKVH 8
#define KVB  32
#define MINIT  -1e30f
#define MASKED -3e30f
#define LOG2E  1.4426950408889634f

static __device__ __forceinline__ unsigned short f2bfu(float f) {
  union { float f; unsigned u; } x; x.f = f;
  return (unsigned short)((x.u + 0x7fffu + ((x.u >> 16) & 1u)) >> 16);
}
static __device__ __forceinline__ float bfu2f(unsigned short u) {
  union { unsigned u; float f; } x; x.u = ((unsigned)u) << 16;
  return x.f;
}
static __device__ __forceinline__ unsigned cvt_pk_bf16(float lo, float hi) {
  unsigned r;
  asm("v_cvt_pk_bf16_f32 %0, %1, %2" : "=v"(r) : "v"(lo), "v"(hi));
  return r;
}
static __device__ __forceinline__ f32x4 mfma_bf16(u16x8 a, u16x8 b, f32x4 c) {
  return __builtin_amdgcn_mfma_f32_16x16x32_bf16(
      __builtin_bit_cast(bf16x8, a), __builtin_bit_cast(bf16x8, b), c, 0, 0, 0);
}
static __device__ __forceinline__ int vswz_k(int row) {
  return (row & 3) | (((row >> 3) & 1) << 2);
}

// ---- fused prepass: K -> bf16 (blocks 0..1023), V -> bf16 transposed (1024..3071) ----
__global__ __launch_bounds__(256) void conv_kv(const float* __restrict__ k,
                                               const float* __restrict__ v,
                                               unsigned* __restrict__ kdst,
                                               unsigned short* __restrict__ vt) {
  __shared__ unsigned T32[32][17];
  const int bb = blockIdx.x;
  if (bb < 1024) {
    const int i = bb * 256 + threadIdx.x;
    const float4 f0 = ((const float4*)k)[2 * i];
    const float4 f1 = ((const float4*)k)[2 * i + 1];
    u32x4 o = { cvt_pk_bf16(f0.x, f0.y), cvt_pk_bf16(f0.z, f0.w),
                cvt_pk_bf16(f1.x, f1.y), cvt_pk_bf16(f1.z, f1.w) };
    ((u32x4*)kdst)[i] = o;
    return;
  }
  const int b   = bb - 1024;
  const int dt  = b & 3;
  const int st  = (b >> 2) & 63;
  const int kvh = b >> 8;
  const int r  = threadIdx.x >> 3;
  const int cg = threadIdx.x & 7;
  const float4 f = *(const float4*)(v + ((size_t)(kvh * SLEN + st * 32 + r) * DDIM) + dt * 32 + cg * 4);
  T32[r][cg * 2]     = cvt_pk_bf16(f.x, f.y);
  T32[r][cg * 2 + 1] = cvt_pk_bf16(f.z, f.w);
  __syncthreads();
  const int dr = threadIdx.x >> 3;
  const unsigned sel = (dr & 1) ? 0x07060302u : 0x05040100u;
  const unsigned a0 = T32[cg * 4 + 0][dr >> 1], a1 = T32[cg * 4 + 1][dr >> 1];
  const unsigned a2 = T32[cg * 4 + 2][dr >> 1], a3 = T32[cg * 4 + 3][dr >> 1];
  unsigned short* vp = vt + (size_t)kvh * DDIM * SLEN + (size_t)(dt * 32 + dr) * SLEN + st * 32 + cg * 4;
  const unsigned w0 = __builtin_amdgcn_perm(a1, a0, sel);
  const unsigned w1 = __builtin_amdgcn_perm(a3, a2, sel);
  vp[0] = (unsigned short)(w0 & 0xffff);
  vp[1] = (unsigned short)(w0 >> 16);
  vp[2] = (unsigned short)(w1 & 0xffff);
  vp[3] = (unsigned short)(w1 >> 16);
}

// ---- attention: swapped QK^T + K-row perm (in-reg P), LDS dbuf, 1 barrier/tile ----
template <int NCH>
__global__ __launch_bounds__(256, 4) void attn_fwd(
    const float* __restrict__ q, const unsigned short* __restrict__ kbf,
    const unsigned short* __restrict__ vtg, const float* __restrict__ sinks,
    const int* __restrict__ bwp, float* __restrict__ out,
    unsigned short* __restrict__ pO, float* __restrict__ pm,
    float* __restrict__ pl) {
  constexpr int NQT = 32;                 // 2048 / 64
  __shared__ unsigned short Kl[2][KVB * DDIM];   // dbuf, unpadded, slot-swizzled
  __shared__ unsigned short Vt[2][DDIM * KVB];
  __shared__ float SmS[4][16];

  const int tid  = threadIdx.x;
  const int wid  = tid >> 6;
  const int lane = tid & 63;
  const int ln   = lane & 15;
  const int hi   = lane >> 4;

  const int B   = blockIdx.x;
  const int x   = B & 7;                  // XCD-resident kvh
  const int j   = B >> 3;
  constexpr int per = 4 * NCH;
  const int qt  = NQT - 1 - (j / per);    // descending: long chunks first
  const int rem = j % per;
  const int hh  = rem / NCH;
  const int c   = rem % NCH;
  const int h   = x * 4 + hh;
  const int kvh = x;
  const int q0  = qt * 64;
  const int qrow0 = q0 + wid * 16;
  const int qpos  = qrow0 + ln;           // lane's q-row

  const int bwv    = bwp[0];
  const int lo_off = (bwv > 0) ? (bwv - 1) : SLEN;

  const int T0 = max(0, q0 - lo_off) >> 5;
  const int T1 = (q0 + 63) >> 5;
  const int N  = T1 - T0 + 1;
  const int ch = (N + NCH - 1) / NCH;
  const int Ts = T0 + c * ch;
  const int Te = min(T1, Ts + ch - 1);

  const float c2 = 0.08838834764831845f * LOG2E;   // sm_scale * log2(e)

  // ---- Q fragments (MFMA B-operand after swap) ----
  u16x8 qf[4];
  {
    const float* qp = q + ((size_t)(h * SLEN + qpos) * DDIM) + hi * 8;
    #pragma unroll
    for (int dk = 0; dk < 4; ++dk) {
      float4 f0 = *(const float4*)(qp + dk * 32);
      float4 f1 = *(const float4*)(qp + dk * 32 + 4);
      u32x4 t = { cvt_pk_bf16(f0.x, f0.y), cvt_pk_bf16(f0.z, f0.w),
                  cvt_pk_bf16(f1.x, f1.y), cvt_pk_bf16(f1.z, f1.w) };
      qf[dk] = __builtin_bit_cast(u16x8, t);
    }
  }

  float m2 = MINIT, l_ln = 0.0f;          // log2-domain stats
  f32x4 oacc[8];
  #pragma unroll
  for (int nt = 0; nt < 8; ++nt) oacc[nt] = f32x4{0.f, 0.f, 0.f, 0.f};

  const unsigned short* Kg = kbf + (size_t)kvh * SLEN * DDIM;
  const unsigned short* Vg = vtg + (size_t)kvh * DDIM * SLEN;

  // ---- staging coords: global linear, LDS slot-swizzled (R11-verified) ----
  const int kr0 = tid >> 4, sk = tid & 15;
  const int kr1 = kr0 + 16;
  const int kw0 = kr0 * DDIM + (((sk & 8) | ((sk & 7) ^ vswz_k(kr0))) * 8);
  const int kw1 = kr1 * DDIM + (((sk & 8) | ((sk & 7) ^ vswz_k(kr1))) * 8);
  const int vr0 = tid >> 2, sv = tid & 3;
  const int vr1 = vr0 + 64;
  const int vw0 = vr0 * KVB + ((sv ^ ((vr0 >> 1) & 3)) * 8);
  const int vw1 = vr1 * KVB + ((sv ^ ((vr1 >> 1) & 3)) * 8);

  // ---- read offsets: K rows permuted so lane holds k = hi*8+0..7 (R11-verified) ----
  const int prow = ((ln >> 2) << 3) | (ln & 3);
  const int vk   = (ln & 3) | (((ln >> 2) & 1) << 2);
  int kfo[4];
  #pragma unroll
  for (int dk = 0; dk < 4; ++dk) {
    const int s = dk * 4 + hi;
    kfo[dk] = prow * DDIM + (((s & 8) | ((s & 7) ^ vk)) * 8);
  }
  const int vro = ln * KVB + ((hi ^ ((ln >> 1) & 3)) * 8);

  if (Ts <= Te) {
    const int kbS = Ts * 32, kbE = Te * 32;

    u16x8 pk0, pk1, pv0, pv1;
    // prologue: load tile kbS, write to buf 0 (visible after first barrier)
    pk0 = *(const u16x8*)(Kg + (size_t)(kbS + kr0) * DDIM + sk * 8);
    pk1 = *(const u16x8*)(Kg + (size_t)(kbS + kr1) * DDIM + sk * 8);
    pv0 = *(const u16x8*)(Vg + (size_t)vr0 * SLEN + kbS + sv * 8);
    pv1 = *(const u16x8*)(Vg + (size_t)vr1 * SLEN + kbS + sv * 8);
    *(u16x8*)&Kl[0][kw0] = pk0;
    *(u16x8*)&Kl[0][kw1] = pk1;
    *(u16x8*)&Vt[0][vw0] = pv0;
    *(u16x8*)&Vt[0][vw1] = pv1;
    // load tile kbS+1 into regs
    {
      const int nb = min(kbS + KVB, kbE);
      pk0 = *(const u16x8*)(Kg + (size_t)(nb + kr0) * DDIM + sk * 8);
      pk1 = *(const u16x8*)(Kg + (size_t)(nb + kr1) * DDIM + sk * 8);
      pv0 = *(const u16x8*)(Vg + (size_t)vr0 * SLEN + nb + sv * 8);
      pv1 = *(const u16x8*)(Vg + (size_t)vr1 * SLEN + nb + sv * 8);
    }

    int cur = 0;
    for (int kb = kbS; kb <= kbE; kb += KVB) {
      __syncthreads();   // buf[cur] (tile kb) fully written & visible
      const int nxt = cur ^ 1;
      // write tile kb+1 (regs) into buf[nxt] — other buffer, no extra barrier
      *(u16x8*)&Kl[nxt][kw0] = pk0;
      *(u16x8*)&Kl[nxt][kw1] = pk1;
      *(u16x8*)&Vt[nxt][vw0] = pv0;
      *(u16x8*)&Vt[nxt][vw1] = pv1;
      // issue loads for tile kb+2
      {
        const int nb = min(kb + 2 * KVB, kbE);
        pk0 = *(const u16x8*)(Kg + (size_t)(nb + kr0) * DDIM + sk * 8);
        pk1 = *(const u16x8*)(Kg + (size_t)(nb + kr1) * DDIM + sk * 8);
        pv0 = *(const u16x8*)(Vg + (size_t)vr0 * SLEN + nb + sv * 8);
        pv1 = *(const u16x8*)(Vg + (size_t)vr1 * SLEN + nb + sv * 8);
      }

      const bool skip = (kb > qrow0 + 15) || (kb + KVB - 1 < qrow0 - lo_off);
      if (!skip) {
        const unsigned short* kbp = &Kl[cur][0];
        const unsigned short* vbp = &Vt[cur][0];

        // ---- QK^T (swapped, K rows permuted): lane gets k = hi*8 + 0..7 ----
        f32x4 sacc0 = {0,0,0,0}, sacc1 = {0,0,0,0};
        __builtin_amdgcn_s_setprio(1);
        #pragma unroll
        for (int dk = 0; dk < 4; ++dk) {
          sacc0 = mfma_bf16(*(const u16x8*)(kbp + kfo[dk]), qf[dk], sacc0);
          sacc1 = mfma_bf16(*(const u16x8*)(kbp + kfo[dk] + 4 * DDIM), qf[dk], sacc1);
        }
        __builtin_amdgcn_s_setprio(0);

        // ---- scale to log2 domain + mask (interior fast path) ----
        float p[8];
        const bool interior = (kb + KVB - 1 <= qrow0) && (kb >= qrow0 + 15 - lo_off);
        if (interior) {
          #pragma unroll
          for (int r = 0; r < 4; ++r) {
            p[r]     = sacc0[r] * c2;
            p[4 + r] = sacc1[r] * c2;
          }
        } else {
          #pragma unroll
          for (int r = 0; r < 4; ++r) {
            const int kp0 = kb + hi * 8 + r;
            const int kp1 = kp0 + 4;
            p[r]     = ((kp0 <= qpos) && (kp0 >= qpos - lo_off)) ? sacc0[r] * c2 : MASKED;
            p[4 + r] = ((kp1 <= qpos) && (kp1 >= qpos - lo_off)) ? sacc1[r] * c2 : MASKED;
          }
        }

        // ---- row max: 7 in-reg + 2 shfl ----
        float mx = fmaxf(fmaxf(fmaxf(p[0], p[1]), fmaxf(p[2], p[3])),
                         fmaxf(fmaxf(p[4], p[5]), fmaxf(p[6], p[7])));
        mx = fmaxf(mx, __shfl_xor(mx, 16));
        mx = fmaxf(mx, __shfl_xor(mx, 32));

        // ---- defer-max rescale (THR = 8 nats in log2 units) ----
        if (__any(mx > m2 + 11.5415605f)) {
          const float mn   = fmaxf(m2, mx);
          const float corr = exp2f(m2 - mn);
          l_ln *= corr;
          m2 = mn;
          if (hi == 0) SmS[wid][ln] = corr;
          float c4[4];
          #pragma unroll
          for (int r = 0; r < 4; ++r) c4[r] = SmS[wid][hi * 4 + r];
          #pragma unroll
          for (int nt = 0; nt < 8; ++nt)
            #pragma unroll
            for (int r = 0; r < 4; ++r) oacc[nt][r] *= c4[r];
        }

        // ---- exp2 + row sum ----
        float s = 0.0f;
        #pragma unroll
        for (int jj = 0; jj < 8; ++jj) { p[jj] = exp2f(p[jj] - m2); s += p[jj]; }
        s += __shfl_xor(s, 16);
        s += __shfl_xor(s, 32);
        l_ln += s;

        // ---- P -> bf16 A-frag, entirely in registers ----
        const u32x4 paw = { cvt_pk_bf16(p[0], p[1]), cvt_pk_bf16(p[2], p[3]),
                            cvt_pk_bf16(p[4], p[5]), cvt_pk_bf16(p[6], p[7]) };
        const u16x8 pa = __builtin_bit_cast(u16x8, paw);

        // ---- PV ----
        __builtin_amdgcn_s_setprio(1);
        #pragma unroll
        for (int nt = 0; nt < 8; ++nt) {
          const u16x8 vb = *(const u16x8*)(vbp + vro + nt * 16 * KVB);
          oacc[nt] = mfma_bf16(pa, vb, oacc[nt]);
        }
        __builtin_amdgcn_s_setprio(0);
      }
      cur ^= 1;
    }
  }

  // ---- epilogue (log2 domain) ----
  if (NCH == 1) {
    const float sk2 = sinks[h] * LOG2E;
    const float M  = fmaxf(m2, sk2);
    const float ed = exp2f(m2 - M);
    const float fac_ln = ed / (l_ln * ed + exp2f(sk2 - M));
    if (hi == 0) SmS[wid][ln] = fac_ln;
    float fac4[4];
    #pragma unroll
    for (int r = 0; r < 4; ++r) fac4[r] = SmS[wid][hi * 4 + r];
    #pragma unroll
    for (int r = 0; r < 4; ++r) {
      float* op = out + ((size_t)(h * SLEN + qrow0 + hi*4 + r) * DDIM) + ln;
      #pragma unroll
      for (int nt = 0; nt < 8; ++nt) op[nt * 16] = oacc[nt][r] * fac4[r];
    }
  } else {
    const size_t Lb = ((size_t)(h * NQT + qt)) * NCH + c;
    if (hi == 0) {
      pm[Lb * 64 + wid * 16 + ln] = m2;    // log2 domain
      pl[Lb * 64 + wid * 16 + ln] = l_ln;
    }
    #pragma unroll
    for (int r = 0; r < 4; ++r) {
      unsigned short* po = pO + (Lb * 64 + wid * 16 + hi * 4 + r) * 128 + ln;
      #pragma unroll
      for (int nt = 0; nt < 8; ++nt) po[nt * 16] = f2bfu(oacc[nt][r]);
    }
  }
}

// ---- merge NCH chunk partials + sink (log2-domain stats) ----
template <int NCH, int QBLK, int NQT>
__global__ __launch_bounds__(256) void mergeN(
    const unsigned short* __restrict__ pO, const float* __restrict__ pm,
    const float* __restrict__ pl, const float* __restrict__ sinks,
    float* __restrict__ out) {
  const int t    = blockIdx.x * 256 + threadIdx.x;
  const int rid  = t >> 2;
  const int d0   = (t & 3) * 32;
  const int h    = rid >> 11;
  const int qpos = rid & 2047;
  const int qt   = qpos / QBLK;
  const int lr   = qpos % QBLK;
  const size_t base = ((size_t)(h * NQT + qt) * NCH) * QBLK + lr;
  const float sk2 = sinks[h] * LOG2E;
  float mc[NCH], lc[NCH];
  float M = sk2;
  #pragma unroll
  for (int c = 0; c < NCH; ++c) {
    mc[c] = pm[base + (size_t)c * QBLK];
    lc[c] = pl[base + (size_t)c * QBLK];
    M = fmaxf(M, mc[c]);
  }
  float denom = exp2f(sk2 - M);
  float sc[NCH];
  #pragma unroll
  for (int c = 0; c < NCH; ++c) { sc[c] = exp2f(mc[c] - M); denom += lc[c] * sc[c]; }
  const float inv = 1.0f / denom;
  float o[32];
  #pragma unroll
  for (int i = 0; i < 32; ++i) o[i] = 0.f;
  #pragma unroll
  for (int c = 0; c < NCH; ++c) {
    const unsigned short* pp = pO + (base + (size_t)c * QBLK) * 128 + d0;
    const float s = sc[c] * inv;
    #pragma unroll
    for (int i = 0; i < 4; ++i) {
      u16x8 a = *(const u16x8*)(pp + i * 8);
      #pragma unroll
      for (int jj = 0; jj < 8; ++jj) o[i*8+jj] += bfu2f(a[jj]) * s;
    }
  }
  float* op = out + (size_t)rid * 128 + d0;
  #pragma unroll
  for (int i = 0; i < 8; ++i)
    *(float4*)(op + i*4) = make_float4(o[i*4], o[i*4+1], o[i*4+2], o[i*4+3]);
}

extern "C" void kernel_launch(void* const* d_in, const int* in_sizes, int n_in,
                              void* d_out, int out_size, void* d_ws, size_t ws_size,
                              hipStream_t stream) {
  const float* q     = (const float*)d_in[0];
  const float* k     = (const float*)d_in[1];
  const float* v     = (const float*)d_in[2];
  const float* sinks = (const float*)d_in[3];
  const int*   bw    = (const int*)d_in[4];
  float* out = (float*)d_out;

  const size_t kvElems = (size_t)NKVH * SLEN * DDIM;
  unsigned short* kbf = (unsigned short*)d_ws;
  unsigned short* vtg = kbf + kvElems;
  unsigned short* pO  = vtg + kvElems;

  // NCH=2: partial rows = 32h * 32qt * 2c * 64 rows
  const size_t nPart2 = (size_t)NH * 32 * 2 * 64;
  const size_t need2  = 4 * kvElems + nPart2 * 128 * 2 + nPart2 * 8;  // ~51.4 MB

  conv_kv<<<dim3(1024 + NKVH * 64 * 4), 256, 0, stream>>>(k, v, (unsigned*)kbf, vtg);

  if (ws_size >= need2) {
    float* pm = (float*)(pO + nPart2 * 128);
    float* pl = pm + nPart2;
    attn_fwd<2><<<dim3(2048), 256, 0, stream>>>(q, kbf, vtg, sinks, bw, out, pO, pm, pl);
    mergeN<2, 64, 32><<<dim3(1024), 256, 0, stream>>>(pO, pm, pl, sinks, out);
  } else {
    attn_fwd<1><<<dim3(1024), 256, 0, stream>>>(q, kbf, vtg, sinks, bw, out, pO, nullptr, nullptr);
  }
}

// Round 14
// 75.371 us; speedup vs baseline: 1.2007x; 1.0316x over previous
//
#include <hip/hip_runtime.h>
#include <hip/hip_bf16.h>

typedef __bf16 bf16x8 __attribute__((ext_vector_type(8)));
typedef unsigned short u16x8 __attribute__((ext_vector_type(8)));
typedef unsigned int u32x4 __attribute__((ext_vector_type(4)));
typedef float f32x4 __attribute__((ext_vector_type(4)));

#define SLEN 2048
#define DDIM 128
#define NH   32
#define NKVH 8
#define KVB  32
#define MINIT  -1e30f
#define MASKED -3e30f
#define LOG2E  1.4426950408889634f

static __device__ __forceinline__ unsigned short f2bfu(float f) {
  union { float f; unsigned u; } x; x.f = f;
  return (unsigned short)((x.u + 0x7fffu + ((x.u >> 16) & 1u)) >> 16);
}
static __device__ __forceinline__ float bfu2f(unsigned short u) {
  union { unsigned u; float f; } x; x.u = ((unsigned)u) << 16;
  return x.f;
}
static __device__ __forceinline__ unsigned cvt_pk_bf16(float lo, float hi) {
  unsigned r;
  asm("v_cvt_pk_bf16_f32 %0, %1, %2" : "=v"(r) : "v"(lo), "v"(hi));
  return r;
}
static __device__ __forceinline__ f32x4 mfma_bf16(u16x8 a, u16x8 b, f32x4 c) {
  return __builtin_amdgcn_mfma_f32_16x16x32_bf16(
      __builtin_bit_cast(bf16x8, a), __builtin_bit_cast(bf16x8, b), c, 0, 0, 0);
}
static __device__ __forceinline__ int vswz_k(int row) {
  return (row & 3) | (((row >> 3) & 1) << 2);
}

// ---- fused prepass: K -> bf16 (blocks 0..1023), V -> bf16 transposed (1024..3071) ----
__global__ __launch_bounds__(256) void conv_kv(const float* __restrict__ k,
                                               const float* __restrict__ v,
                                               unsigned* __restrict__ kdst,
                                               unsigned short* __restrict__ vt) {
  __shared__ unsigned T32[32][17];
  const int bb = blockIdx.x;
  if (bb < 1024) {
    const int i = bb * 256 + threadIdx.x;
    const float4 f0 = ((const float4*)k)[2 * i];
    const float4 f1 = ((const float4*)k)[2 * i + 1];
    u32x4 o = { cvt_pk_bf16(f0.x, f0.y), cvt_pk_bf16(f0.z, f0.w),
                cvt_pk_bf16(f1.x, f1.y), cvt_pk_bf16(f1.z, f1.w) };
    ((u32x4*)kdst)[i] = o;
    return;
  }
  const int b   = bb - 1024;
  const int dt  = b & 3;
  const int st  = (b >> 2) & 63;
  const int kvh = b >> 8;
  const int r  = threadIdx.x >> 3;
  const int cg = threadIdx.x & 7;
  const float4 f = *(const float4*)(v + ((size_t)(kvh * SLEN + st * 32 + r) * DDIM) + dt * 32 + cg * 4);
  T32[r][cg * 2]     = cvt_pk_bf16(f.x, f.y);
  T32[r][cg * 2 + 1] = cvt_pk_bf16(f.z, f.w);
  __syncthreads();
  const int dr = threadIdx.x >> 3;
  const unsigned sel = (dr & 1) ? 0x07060302u : 0x05040100u;
  const unsigned a0 = T32[cg * 4 + 0][dr >> 1], a1 = T32[cg * 4 + 1][dr >> 1];
  const unsigned a2 = T32[cg * 4 + 2][dr >> 1], a3 = T32[cg * 4 + 3][dr >> 1];
  unsigned short* vp = vt + (size_t)kvh * DDIM * SLEN + (size_t)(dt * 32 + dr) * SLEN + st * 32 + cg * 4;
  const unsigned w0 = __builtin_amdgcn_perm(a1, a0, sel);
  const unsigned w1 = __builtin_amdgcn_perm(a3, a2, sel);
  vp[0] = (unsigned short)(w0 & 0xffff);
  vp[1] = (unsigned short)(w0 >> 16);
  vp[2] = (unsigned short)(w1 & 0xffff);
  vp[3] = (unsigned short)(w1 >> 16);
}

// ---- attention: swapped QK^T + K-row perm (in-reg P), single-buffer, lazy l-reduce ----
template <int NCH>
__global__ __launch_bounds__(256, 4) void attn_fwd(
    const float* __restrict__ q, const unsigned short* __restrict__ kbf,
    const unsigned short* __restrict__ vtg, const float* __restrict__ sinks,
    const int* __restrict__ bwp, float* __restrict__ out,
    unsigned short* __restrict__ pO, float* __restrict__ pm,
    float* __restrict__ pl) {
  constexpr int NQT = 32;                 // 2048 / 64
  __shared__ unsigned short Kl[KVB * DDIM];   // unpadded, slot-swizzled
  __shared__ unsigned short Vt[DDIM * KVB];   // unpadded, slot-swizzled
  __shared__ float SmS[4][16];

  const int tid  = threadIdx.x;
  const int wid  = tid >> 6;
  const int lane = tid & 63;
  const int ln   = lane & 15;
  const int hi   = lane >> 4;

  const int B   = blockIdx.x;
  const int x   = B & 7;                  // XCD-resident kvh
  const int j   = B >> 3;
  constexpr int per = 4 * NCH;
  const int qt  = NQT - 1 - (j / per);    // descending: long chunks first
  const int rem = j % per;
  const int hh  = rem / NCH;
  const int c   = rem % NCH;
  const int h   = x * 4 + hh;
  const int kvh = x;
  const int q0  = qt * 64;
  const int qrow0 = q0 + wid * 16;
  const int qpos  = qrow0 + ln;           // lane's q-row

  const int bwv    = bwp[0];
  const int lo_off = (bwv > 0) ? (bwv - 1) : SLEN;

  const int T0 = max(0, q0 - lo_off) >> 5;
  const int T1 = (q0 + 63) >> 5;
  const int N  = T1 - T0 + 1;
  const int ch = (N + NCH - 1) / NCH;
  const int Ts = T0 + c * ch;
  const int Te = min(T1, Ts + ch - 1);

  const float c2 = 0.08838834764831845f * LOG2E;  // sm_scale * log2(e)

  // ---- Q fragments (MFMA B-operand after swap) ----
  u16x8 qf[4];
  {
    const float* qp = q + ((size_t)(h * SLEN + qpos) * DDIM) + hi * 8;
    #pragma unroll
    for (int dk = 0; dk < 4; ++dk) {
      float4 f0 = *(const float4*)(qp + dk * 32);
      float4 f1 = *(const float4*)(qp + dk * 32 + 4);
      u32x4 t = { cvt_pk_bf16(f0.x, f0.y), cvt_pk_bf16(f0.z, f0.w),
                  cvt_pk_bf16(f1.x, f1.y), cvt_pk_bf16(f1.z, f1.w) };
      qf[dk] = __builtin_bit_cast(u16x8, t);
    }
  }

  float m2 = MINIT;       // log2-domain running max (row-uniform across hi lanes)
  float l_ln = 0.0f;      // per-lane PARTIAL sum (reduced once in epilogue)
  f32x4 oacc[8];
  #pragma unroll
  for (int nt = 0; nt < 8; ++nt) oacc[nt] = f32x4{0.f, 0.f, 0.f, 0.f};

  const unsigned short* Kg = kbf + (size_t)kvh * SLEN * DDIM;
  const unsigned short* Vg = vtg + (size_t)kvh * DDIM * SLEN;

  // ---- staging coords: global linear, LDS slot-swizzled (R11-verified) ----
  const int kr0 = tid >> 4, sk = tid & 15;
  const int kr1 = kr0 + 16;
  const int kw0 = kr0 * DDIM + (((sk & 8) | ((sk & 7) ^ vswz_k(kr0))) * 8);
  const int kw1 = kr1 * DDIM + (((sk & 8) | ((sk & 7) ^ vswz_k(kr1))) * 8);
  const int vr0 = tid >> 2, sv = tid & 3;
  const int vr1 = vr0 + 64;
  const int vw0 = vr0 * KVB + ((sv ^ ((vr0 >> 1) & 3)) * 8);
  const int vw1 = vr1 * KVB + ((sv ^ ((vr1 >> 1) & 3)) * 8);

  // ---- read offsets: K rows permuted so lane holds k = hi*8+0..7 (R11-verified) ----
  const int prow = ((ln >> 2) << 3) | (ln & 3);
  const int vk   = (ln & 3) | (((ln >> 2) & 1) << 2);
  int kfo[4];
  #pragma unroll
  for (int dk = 0; dk < 4; ++dk) {
    const int s = dk * 4 + hi;
    kfo[dk] = prow * DDIM + (((s & 8) | ((s & 7) ^ vk)) * 8);
  }
  const int vro = ln * KVB + ((hi ^ ((ln >> 1) & 3)) * 8);

  if (Ts <= Te) {
    const int kbS = Ts * 32, kbE = Te * 32;

    u16x8 pk0, pk1, pv0, pv1;
    {
      pk0 = *(const u16x8*)(Kg + (size_t)(kbS + kr0) * DDIM + sk * 8);
      pk1 = *(const u16x8*)(Kg + (size_t)(kbS + kr1) * DDIM + sk * 8);
      pv0 = *(const u16x8*)(Vg + (size_t)vr0 * SLEN + kbS + sv * 8);
      pv1 = *(const u16x8*)(Vg + (size_t)vr1 * SLEN + kbS + sv * 8);
    }

    for (int kb = kbS; kb <= kbE; kb += KVB) {
      __syncthreads();
      *(u16x8*)&Kl[kw0] = pk0;
      *(u16x8*)&Kl[kw1] = pk1;
      *(u16x8*)&Vt[vw0] = pv0;
      *(u16x8*)&Vt[vw1] = pv1;
      __syncthreads();

      {
        const int nb = min(kb + KVB, kbE);
        pk0 = *(const u16x8*)(Kg + (size_t)(nb + kr0) * DDIM + sk * 8);
        pk1 = *(const u16x8*)(Kg + (size_t)(nb + kr1) * DDIM + sk * 8);
        pv0 = *(const u16x8*)(Vg + (size_t)vr0 * SLEN + nb + sv * 8);
        pv1 = *(const u16x8*)(Vg + (size_t)vr1 * SLEN + nb + sv * 8);
      }

      if (kb > qrow0 + 15) continue;
      if (kb + KVB - 1 < qrow0 - lo_off) continue;

      // ---- QK^T (swapped, K rows permuted): lane gets k = hi*8 + 0..7 ----
      f32x4 sacc0 = {0,0,0,0}, sacc1 = {0,0,0,0};
      __builtin_amdgcn_s_setprio(1);
      #pragma unroll
      for (int dk = 0; dk < 4; ++dk) {
        sacc0 = mfma_bf16(*(const u16x8*)&Kl[kfo[dk]], qf[dk], sacc0);
        sacc1 = mfma_bf16(*(const u16x8*)&Kl[kfo[dk] + 4 * DDIM], qf[dk], sacc1);
      }
      __builtin_amdgcn_s_setprio(0);

      // ---- scale to log2 domain + mask (interior fast path, wave-uniform) ----
      float p[8];
      const bool interior = (kb + KVB - 1 <= qrow0) && (kb >= qrow0 + 15 - lo_off);
      if (interior) {
        #pragma unroll
        for (int r = 0; r < 4; ++r) {
          p[r]     = sacc0[r] * c2;
          p[4 + r] = sacc1[r] * c2;
        }
      } else {
        #pragma unroll
        for (int r = 0; r < 4; ++r) {
          const int kp0 = kb + hi * 8 + r;
          const int kp1 = kp0 + 4;
          p[r]     = ((kp0 <= qpos) && (kp0 >= qpos - lo_off)) ? sacc0[r] * c2 : MASKED;
          p[4 + r] = ((kp1 <= qpos) && (kp1 >= qpos - lo_off)) ? sacc1[r] * c2 : MASKED;
        }
      }

      // ---- row max: 7 in-reg + 2 shfl (required: m2 must be row-uniform) ----
      float mx = fmaxf(fmaxf(fmaxf(p[0], p[1]), fmaxf(p[2], p[3])),
                       fmaxf(fmaxf(p[4], p[5]), fmaxf(p[6], p[7])));
      mx = fmaxf(mx, __shfl_xor(mx, 16));
      mx = fmaxf(mx, __shfl_xor(mx, 32));

      // ---- defer-max rescale (THR = 8 nats in log2 units) ----
      if (__any(mx > m2 + 11.5415605f)) {
        const float mn   = fmaxf(m2, mx);
        const float corr = exp2f(m2 - mn);   // row-uniform
        l_ln *= corr;
        m2 = mn;
        if (hi == 0) SmS[wid][ln] = corr;
        float c4[4];
        #pragma unroll
        for (int r = 0; r < 4; ++r) c4[r] = SmS[wid][hi * 4 + r];
        #pragma unroll
        for (int nt = 0; nt < 8; ++nt)
          #pragma unroll
          for (int r = 0; r < 4; ++r) oacc[nt][r] *= c4[r];
      }

      // ---- exp2 + per-lane partial sum (NO shfl here — reduced in epilogue) ----
      float s = 0.0f;
      #pragma unroll
      for (int jj = 0; jj < 8; ++jj) { p[jj] = exp2f(p[jj] - m2); s += p[jj]; }
      l_ln += s;

      // ---- P -> bf16 A-frag, entirely in registers ----
      const u32x4 paw = { cvt_pk_bf16(p[0], p[1]), cvt_pk_bf16(p[2], p[3]),
                          cvt_pk_bf16(p[4], p[5]), cvt_pk_bf16(p[6], p[7]) };
      const u16x8 pa = __builtin_bit_cast(u16x8, paw);

      // ---- PV ----
      __builtin_amdgcn_s_setprio(1);
      #pragma unroll
      for (int nt = 0; nt < 8; ++nt) {
        const u16x8 vb = *(const u16x8*)&Vt[vro + nt * 16 * KVB];
        oacc[nt] = mfma_bf16(pa, vb, oacc[nt]);
      }
      __builtin_amdgcn_s_setprio(0);
    }
  }

  // ---- lazy l reduction (once): sum partials across the 4 hi-lanes of row ln ----
  l_ln += __shfl_xor(l_ln, 16);
  l_ln += __shfl_xor(l_ln, 32);

  // ---- epilogue (log2 domain) ----
  if (NCH == 1) {
    const float sk2 = sinks[h] * LOG2E;
    const float M  = fmaxf(m2, sk2);
    const float ed = exp2f(m2 - M);
    const float fac_ln = ed / (l_ln * ed + exp2f(sk2 - M));
    if (hi == 0) SmS[wid][ln] = fac_ln;
    float fac4[4];
    #pragma unroll
    for (int r = 0; r < 4; ++r) fac4[r] = SmS[wid][hi * 4 + r];
    #pragma unroll
    for (int r = 0; r < 4; ++r) {
      float* op = out + ((size_t)(h * SLEN + qrow0 + hi*4 + r) * DDIM) + ln;
      #pragma unroll
      for (int nt = 0; nt < 8; ++nt) op[nt * 16] = oacc[nt][r] * fac4[r];
    }
  } else {
    const size_t Lb = ((size_t)(h * NQT + qt)) * NCH + c;
    if (hi == 0) {
      pm[Lb * 64 + wid * 16 + ln] = m2;    // log2 domain
      pl[Lb * 64 + wid * 16 + ln] = l_ln;
    }
    #pragma unroll
    for (int r = 0; r < 4; ++r) {
      unsigned short* po = pO + (Lb * 64 + wid * 16 + hi * 4 + r) * 128 + ln;
      #pragma unroll
      for (int nt = 0; nt < 8; ++nt) po[nt * 16] = f2bfu(oacc[nt][r]);
    }
  }
}

// ---- merge NCH chunk partials + sink (log2-domain stats, XCD-local mapping) ----
template <int NCH, int QBLK, int NQT>
__global__ __launch_bounds__(256) void mergeN(
    const unsigned short* __restrict__ pO, const float* __restrict__ pm,
    const float* __restrict__ pl, const float* __restrict__ sinks,
    float* __restrict__ out) {
  // block -> (x, hh, sub) so that head h = x*4+hh reads partials produced on XCD x
  const int b   = blockIdx.x;
  const int x   = b & 7;
  const int jj2 = b >> 3;            // 0..127
  const int h   = x * 4 + (jj2 >> 5);
  const int sub = jj2 & 31;          // 64-row slab within head
  const int rloc = sub * 64 + (threadIdx.x >> 2);
  const int rid  = h * 2048 + rloc;
  const int d0   = (threadIdx.x & 3) * 32;
  const int qt   = rloc / QBLK;
  const int lr   = rloc % QBLK;
  const size_t base = ((size_t)(h * NQT + qt) * NCH) * QBLK + lr;
  const float sk2 = sinks[h] * LOG2E;
  float mc[NCH], lc[NCH];
  float M = sk2;
  #pragma unroll
  for (int c = 0; c < NCH; ++c) {
    mc[c] = pm[base + (size_t)c * QBLK];
    lc[c] = pl[base + (size_t)c * QBLK];
    M = fmaxf(M, mc[c]);
  }
  float denom = exp2f(sk2 - M);
  float sc[NCH];
  #pragma unroll
  for (int c = 0; c < NCH; ++c) { sc[c] = exp2f(mc[c] - M); denom += lc[c] * sc[c]; }
  const float inv = 1.0f / denom;
  float o[32];
  #pragma unroll
  for (int i = 0; i < 32; ++i) o[i] = 0.f;
  #pragma unroll
  for (int c = 0; c < NCH; ++c) {
    const unsigned short* pp = pO + (base + (size_t)c * QBLK) * 128 + d0;
    const float s = sc[c] * inv;
    #pragma unroll
    for (int i = 0; i < 4; ++i) {
      u16x8 a = *(const u16x8*)(pp + i * 8);
      #pragma unroll
      for (int jj = 0; jj < 8; ++jj) o[i*8+jj] += bfu2f(a[jj]) * s;
    }
  }
  float* op = out + (size_t)rid * 128 + d0;
  #pragma unroll
  for (int i = 0; i < 8; ++i)
    *(float4*)(op + i*4) = make_float4(o[i*4], o[i*4+1], o[i*4+2], o[i*4+3]);
}

extern "C" void kernel_launch(void* const* d_in, const int* in_sizes, int n_in,
                              void* d_out, int out_size, void* d_ws, size_t ws_size,
                              hipStream_t stream) {
  const float* q     = (const float*)d_in[0];
  const float* k     = (const float*)d_in[1];
  const float* v     = (const float*)d_in[2];
  const float* sinks = (const float*)d_in[3];
  const int*   bw    = (const int*)d_in[4];
  float* out = (float*)d_out;

  const size_t kvElems = (size_t)NKVH * SLEN * DDIM;
  unsigned short* kbf = (unsigned short*)d_ws;
  unsigned short* vtg = kbf + kvElems;
  unsigned short* pO  = vtg + kvElems;

  // NCH=2: partial rows = 32h * 32qt * 2c * 64 rows
  const size_t nPart2 = (size_t)NH * 32 * 2 * 64;
  const size_t need2  = 4 * kvElems + nPart2 * 128 * 2 + nPart2 * 8;  // ~51.4 MB

  conv_kv<<<dim3(1024 + NKVH * 64 * 4), 256, 0, stream>>>(k, v, (unsigned*)kbf, vtg);

  if (ws_size >= need2) {
    float* pm = (float*)(pO + nPart2 * 128);
    float* pl = pm + nPart2;
    attn_fwd<2><<<dim3(2048), 256, 0, stream>>>(q, kbf, vtg, sinks, bw, out, pO, pm, pl);
    mergeN<2, 64, 32><<<dim3(1024), 256, 0, stream>>>(pO, pm, pl, sinks, out);
  } else {
    attn_fwd<1><<<dim3(1024), 256, 0, stream>>>(q, kbf, vtg, sinks, bw, out, pO, nullptr, nullptr);
  }
}